// Round 1
// baseline (337.823 us; speedup 1.0000x reference)
//
#include <hip/hip_runtime.h>
#include <hip/hip_bf16.h>

#define B_ 4
#define T_ 4096
#define C_ 1024
#define H_ 64

typedef __bf16 bf16x8 __attribute__((ext_vector_type(8)));
typedef float f32x4 __attribute__((ext_vector_type(4)));
typedef unsigned short u16x8 __attribute__((ext_vector_type(8)));

union Frag8 { uint4 u; bf16x8 b; u16x8 s; };

__device__ inline unsigned short bfbits(float f) {
  union { __hip_bfloat16 h; unsigned short u; } cv;
  cv.h = __float2bfloat16(f);
  return cv.u;
}

__device__ inline bf16x8 ldb8(const unsigned short* p) {
  Frag8 f; f.u = *(const uint4*)p; return f.b;
}

// ---------------- k0: convert W (3 x [64,1024] fp32) to bf16 ----------------
__global__ __launch_bounds__(256) void wconv(const float* __restrict__ Wq,
                                             const float* __restrict__ Wk,
                                             const float* __restrict__ Wv,
                                             unsigned short* __restrict__ Wb) {
  int i = blockIdx.x * 256 + threadIdx.x;        // 192 blocks -> 49152 threads
  size_t e = (size_t)i * 4;                      // element index in [0, 196608)
  const float* src = (e < 65536) ? (Wq + e)
                   : (e < 131072 ? (Wk + (e - 65536)) : (Wv + (e - 131072)));
  float4 v = *(const float4*)src;
  unsigned long long o =
      (unsigned long long)bfbits(v.x)
    | ((unsigned long long)bfbits(v.y) << 16)
    | ((unsigned long long)bfbits(v.z) << 32)
    | ((unsigned long long)bfbits(v.w) << 48);
  *(unsigned long long*)(Wb + e) = o;
}

// ---------------- k1: QKV projection GEMM (bf16 MFMA) ----------------
// out[m][h] = sum_c x[m][c] * W[h][c];  M=16384, K=1024, N=192 (Q|K|V)
// Block: 256 thr = 4 waves = (2 row-groups of 16) x (2 col-halves of 96).
__global__ __launch_bounds__(256) void qkv_proj(const float* __restrict__ x,
                                                const unsigned short* __restrict__ Wb,
                                                unsigned short* __restrict__ qkv) {
  const int lane = threadIdx.x & 63;
  const int wave = threadIdx.x >> 6;
  const int rg = wave & 1, ch = wave >> 1;
  const int q16 = lane & 15, quad = lane >> 4;
  const size_t row0 = (size_t)blockIdx.x * 32 + rg * 16;
  const float* xp = x + (row0 + q16) * C_ + quad * 8;

  const unsigned short* wp[6];
#pragma unroll
  for (int f = 0; f < 6; ++f) {
    int gcol = ch * 96 + f * 16;        // 0..176
    int mat = gcol >> 6, hb = gcol & 63;
    wp[f] = Wb + (size_t)mat * 65536 + (size_t)(hb + q16) * C_ + quad * 8;
  }

  f32x4 acc[6] = {};
  for (int c0 = 0; c0 < C_; c0 += 32) {
    float4 a0 = *(const float4*)(xp + c0);
    float4 a1 = *(const float4*)(xp + c0 + 4);
    Frag8 af;
    af.s[0] = bfbits(a0.x); af.s[1] = bfbits(a0.y);
    af.s[2] = bfbits(a0.z); af.s[3] = bfbits(a0.w);
    af.s[4] = bfbits(a1.x); af.s[5] = bfbits(a1.y);
    af.s[6] = bfbits(a1.z); af.s[7] = bfbits(a1.w);
#pragma unroll
    for (int f = 0; f < 6; ++f) {
      bf16x8 bfrag = ldb8(wp[f] + c0);
      acc[f] = __builtin_amdgcn_mfma_f32_16x16x32_bf16(af.b, bfrag, acc[f], 0, 0, 0);
    }
  }

#pragma unroll
  for (int f = 0; f < 6; ++f) {
    int gcol = ch * 96 + f * 16;
    int mat = gcol >> 6, hb = gcol & 63;
    int h = hb + q16;
    float scale = (mat == 0) ? 0.125f : 1.0f;   // Q pre-scaled by 1/sqrt(64)
#pragma unroll
    for (int r = 0; r < 4; ++r) {
      size_t row = row0 + quad * 4 + r;         // C/D layout: row = quad*4+reg
      qkv[(size_t)mat * 1048576 + row * H_ + h] = bfbits(acc[f][r] * scale);
    }
  }
}

// ---------------- k1b: transpose V [B*T][64] -> Vt [B][64][T] ----------------
__global__ __launch_bounds__(256) void vtrans(const unsigned short* __restrict__ Vsrc,
                                              unsigned short* __restrict__ Vt) {
  __shared__ unsigned short tile[64][65];
  const int t0 = blockIdx.x * 64;
  const int bb = blockIdx.y;
  const int tid = threadIdx.x;
#pragma unroll
  for (int i = 0; i < 2; ++i) {
    int c = tid + 256 * i;                 // 0..511 (16B chunks)
    int tt = c >> 3, h0 = (c & 7) * 8;
    union { uint4 u; unsigned short s[8]; } cv;
    cv.u = *(const uint4*)(Vsrc + ((size_t)(bb * T_ + t0 + tt)) * H_ + h0);
#pragma unroll
    for (int j = 0; j < 8; ++j) tile[tt][h0 + j] = cv.s[j];
  }
  __syncthreads();
#pragma unroll
  for (int i = 0; i < 2; ++i) {
    int c = tid + 256 * i;
    int h = c >> 3, tt0 = (c & 7) * 8;
    union { uint4 u; unsigned short s[8]; } cv;
#pragma unroll
    for (int j = 0; j < 8; ++j) cv.s[j] = tile[tt0 + j][h];
    *(uint4*)(Vt + ((size_t)bb * H_ + h) * T_ + t0 + tt0) = cv.u;
  }
}

// ---------------- k2: flash causal attention, 1 wave per 16-row Q-tile ------
// S^T = K Q^T via mfma(A=K, B=Q): C layout holds S^T[kk=quad*4+reg][q=lane&15].
// P^T C-frags are exchanged (half-quad bpermute) into PV A-operand layout.
__global__ __launch_bounds__(256) void attn(const unsigned short* __restrict__ Q,
                                            const unsigned short* __restrict__ K,
                                            const unsigned short* __restrict__ Vt,
                                            float* __restrict__ out) {
  const int lane = threadIdx.x & 63;
  const int wave = threadIdx.x >> 6;
  const int b = blockIdx.x;                 // batch
  const int ty = 63 - blockIdx.y;           // reversed: longest blocks first
  const int tile = 4 * ty + wave;           // q-tile index 0..255 (16 rows each)
  const int q16 = lane & 15, quad = lane >> 4;

  const unsigned short* Qb = Q + (size_t)b * T_ * H_;
  const unsigned short* Kb = K + (size_t)b * T_ * H_;
  const unsigned short* Vtb = Vt + (size_t)b * H_ * T_;

  const int q0 = tile * 16;
  bf16x8 qf0 = ldb8(Qb + (size_t)(q0 + q16) * H_ + quad * 8);
  bf16x8 qf1 = ldb8(Qb + (size_t)(q0 + q16) * H_ + 32 + quad * 8);

  f32x4 o0 = {0.f, 0.f, 0.f, 0.f}, o1 = o0, o2 = o0, o3 = o0;
  float m = -3.0e38f, l = 0.0f;
  const int ktiles = (tile >> 2) + 1;       // == ty+1, same for all 4 waves

  for (int kt = 0; kt < ktiles; ++kt) {
    const int kkb = kt * 64;
    f32x4 st[4];
#pragma unroll
    for (int kb = 0; kb < 4; ++kb) {
      const unsigned short* kp = Kb + (size_t)(kkb + kb * 16 + q16) * H_ + quad * 8;
      bf16x8 ka0 = ldb8(kp);
      bf16x8 ka1 = ldb8(kp + 32);
      f32x4 s = {0.f, 0.f, 0.f, 0.f};
      s = __builtin_amdgcn_mfma_f32_16x16x32_bf16(ka0, qf0, s, 0, 0, 0);
      s = __builtin_amdgcn_mfma_f32_16x16x32_bf16(ka1, qf1, s, 0, 0, 0);
      st[kb] = s;
    }
    if (kt == ktiles - 1) {                 // only the diagonal tile needs mask
      const int q_abs = q0 + q16;
#pragma unroll
      for (int kb = 0; kb < 4; ++kb)
#pragma unroll
        for (int r = 0; r < 4; ++r) {
          int kk_abs = kkb + kb * 16 + quad * 4 + r;
          if (kk_abs > q_abs) st[kb][r] = -3.0e38f;
        }
    }
    // row stats: per-lane q = q16; kk spread over regs (in-lane) + quads (xor)
    float mloc = fmaxf(fmaxf(st[0][0], st[0][1]), fmaxf(st[0][2], st[0][3]));
#pragma unroll
    for (int kb = 1; kb < 4; ++kb)
      mloc = fmaxf(mloc, fmaxf(fmaxf(st[kb][0], st[kb][1]), fmaxf(st[kb][2], st[kb][3])));
    mloc = fmaxf(mloc, __shfl_xor(mloc, 16));
    mloc = fmaxf(mloc, __shfl_xor(mloc, 32));
    float mnew = fmaxf(m, mloc);
    float alpha = __expf(m - mnew);
    float lsum = 0.f;
    unsigned pk[4][2];
#pragma unroll
    for (int kb = 0; kb < 4; ++kb) {
      float p0 = __expf(st[kb][0] - mnew);
      float p1 = __expf(st[kb][1] - mnew);
      float p2 = __expf(st[kb][2] - mnew);
      float p3 = __expf(st[kb][3] - mnew);
      lsum += (p0 + p1) + (p2 + p3);
      pk[kb][0] = (unsigned)bfbits(p0) | ((unsigned)bfbits(p1) << 16);
      pk[kb][1] = (unsigned)bfbits(p2) | ((unsigned)bfbits(p3) << 16);
    }
    lsum += __shfl_xor(lsum, 16);
    lsum += __shfl_xor(lsum, 32);
    l = l * alpha + lsum;
    m = mnew;
    // rescale O: row of o-frag = quad*4+reg; alpha lives at lane==row (group 0)
    float ar0 = __shfl(alpha, quad * 4 + 0);
    float ar1 = __shfl(alpha, quad * 4 + 1);
    float ar2 = __shfl(alpha, quad * 4 + 2);
    float ar3 = __shfl(alpha, quad * 4 + 3);
    o0[0] *= ar0; o0[1] *= ar1; o0[2] *= ar2; o0[3] *= ar3;
    o1[0] *= ar0; o1[1] *= ar1; o1[2] *= ar2; o1[3] *= ar3;
    o2[0] *= ar0; o2[1] *= ar1; o2[2] *= ar2; o2[3] *= ar3;
    o3[0] *= ar0; o3[1] *= ar1; o3[2] *= ar2; o3[3] *= ar3;

    // P^T (C layout) -> PV A-operand layout (K=32): half-quad exchange
    const int kbsel = quad >> 1;
    const int src0 = q16 + 32 * (quad & 1);
#pragma unroll
    for (int kb2 = 0; kb2 < 2; ++kb2) {
      int xA = __shfl((int)pk[2 * kb2][0], src0);
      int xB = __shfl((int)pk[2 * kb2 + 1][0], src0);
      int yA = __shfl((int)pk[2 * kb2][1], src0);
      int yB = __shfl((int)pk[2 * kb2 + 1][1], src0);
      int zA = __shfl((int)pk[2 * kb2][0], src0 + 16);
      int zB = __shfl((int)pk[2 * kb2 + 1][0], src0 + 16);
      int wA = __shfl((int)pk[2 * kb2][1], src0 + 16);
      int wB = __shfl((int)pk[2 * kb2 + 1][1], src0 + 16);
      Frag8 pf;
      pf.u.x = (unsigned)(kbsel ? xB : xA);
      pf.u.y = (unsigned)(kbsel ? yB : yA);
      pf.u.z = (unsigned)(kbsel ? zB : zA);
      pf.u.w = (unsigned)(kbsel ? wB : wA);
      const unsigned short* vp = Vtb + (size_t)q16 * T_ + kkb + kb2 * 32 + quad * 8;
      o0 = __builtin_amdgcn_mfma_f32_16x16x32_bf16(pf.b, ldb8(vp), o0, 0, 0, 0);
      o1 = __builtin_amdgcn_mfma_f32_16x16x32_bf16(pf.b, ldb8(vp + (size_t)16 * T_), o1, 0, 0, 0);
      o2 = __builtin_amdgcn_mfma_f32_16x16x32_bf16(pf.b, ldb8(vp + (size_t)32 * T_), o2, 0, 0, 0);
      o3 = __builtin_amdgcn_mfma_f32_16x16x32_bf16(pf.b, ldb8(vp + (size_t)48 * T_), o3, 0, 0, 0);
    }
  }

  float linv = 1.0f / l;
#pragma unroll
  for (int r = 0; r < 4; ++r) {
    float lr = __shfl(linv, quad * 4 + r);
    size_t rowoff = ((size_t)b * T_ + q0 + quad * 4 + r) * H_ + q16;
    out[rowoff + 0]  = o0[r] * lr;
    out[rowoff + 16] = o1[r] * lr;
    out[rowoff + 32] = o2[r] * lr;
    out[rowoff + 48] = o3[r] * lr;
  }
}

extern "C" void kernel_launch(void* const* d_in, const int* in_sizes, int n_in,
                              void* d_out, int out_size, void* d_ws, size_t ws_size,
                              hipStream_t stream) {
  const float* x  = (const float*)d_in[0];
  const float* Wq = (const float*)d_in[1];
  const float* Wk = (const float*)d_in[2];
  const float* Wv = (const float*)d_in[3];
  float* out = (float*)d_out;
  unsigned short* ws = (unsigned short*)d_ws;

  // ws layout (ushort units):
  //   [0, 196608)             Wb  (Q|K|V bf16 weights)
  //   [196608, +1048576)      Q bf16 [B*T][64]  (pre-scaled)
  //   next 1048576            K bf16 [B*T][64]
  //   next 1048576            V bf16 [B*T][64] (row-major temp)
  //   next 1048576            Vt bf16 [B][64][T]
  unsigned short* Wb   = ws;
  unsigned short* qkv  = ws + 196608;
  unsigned short* Vrow = qkv + (size_t)2 * 1048576;
  unsigned short* Vt   = qkv + (size_t)3 * 1048576;

  wconv<<<192, 256, 0, stream>>>(Wq, Wk, Wv, Wb);
  qkv_proj<<<512, 256, 0, stream>>>(x, Wb, qkv);
  vtrans<<<dim3(64, 4), 256, 0, stream>>>(Vrow, Vt);
  attn<<<dim3(4, 64), 256, 0, stream>>>(qkv, qkv + 1048576, Vt, out);
}

// Round 2
// 229.009 us; speedup vs baseline: 1.4751x; 1.4751x over previous
//
#include <hip/hip_runtime.h>
#include <hip/hip_bf16.h>

#define B_ 4
#define T_ 4096
#define C_ 1024
#define H_ 64

typedef __bf16 bf16x8 __attribute__((ext_vector_type(8)));
typedef float f32x4 __attribute__((ext_vector_type(4)));
typedef unsigned short u16x8 __attribute__((ext_vector_type(8)));

union Frag8 { uint4 u; bf16x8 b; u16x8 s; };

__device__ inline unsigned short bfbits(float f) {
  union { __hip_bfloat16 h; unsigned short u; } cv;
  cv.h = __float2bfloat16(f);
  return cv.u;
}

__device__ inline bf16x8 ldb8(const unsigned short* p) {
  Frag8 f; f.u = *(const uint4*)p; return f.b;
}

// ---------------- k0: convert W (3 x [64,1024] fp32) to bf16 ----------------
__global__ __launch_bounds__(256) void wconv(const float* __restrict__ Wq,
                                             const float* __restrict__ Wk,
                                             const float* __restrict__ Wv,
                                             unsigned short* __restrict__ Wb) {
  int i = blockIdx.x * 256 + threadIdx.x;        // 192 blocks -> 49152 threads
  size_t e = (size_t)i * 4;                      // element index in [0, 196608)
  const float* src = (e < 65536) ? (Wq + e)
                   : (e < 131072 ? (Wk + (e - 65536)) : (Wv + (e - 131072)));
  float4 v = *(const float4*)src;
  unsigned long long o =
      (unsigned long long)bfbits(v.x)
    | ((unsigned long long)bfbits(v.y) << 16)
    | ((unsigned long long)bfbits(v.z) << 32)
    | ((unsigned long long)bfbits(v.w) << 48);
  *(unsigned long long*)(Wb + e) = o;
}

// ---------------- k1: QKV projection GEMM (bf16 MFMA) ----------------
// out[m][h] = sum_c x[m][c] * W[h][c];  M=16384, K=1024, N=192 (Q|K|V)
// Block = 16 rows, 4 waves x 48 cols. V is written TRANSPOSED to Vt [B][64][T]
// directly from the C-layout epilogue (rows are contiguous t -> ushort4 store).
__global__ __launch_bounds__(256) void qkv_proj(const float* __restrict__ x,
                                                const unsigned short* __restrict__ Wb,
                                                unsigned short* __restrict__ qkv,
                                                unsigned short* __restrict__ Vt) {
  const int lane = threadIdx.x & 63;
  const int wave = threadIdx.x >> 6;
  const int q16 = lane & 15, quad = lane >> 4;
  const size_t row0 = (size_t)blockIdx.x * 16;
  const float* xp = x + (row0 + q16) * C_ + quad * 8;

  const unsigned short* wp[3];
#pragma unroll
  for (int f = 0; f < 3; ++f) {
    int gcol = wave * 48 + f * 16;      // 0..176
    int mat = gcol >> 6, hb = gcol & 63;
    wp[f] = Wb + (size_t)mat * 65536 + (size_t)(hb + q16) * C_ + quad * 8;
  }

  f32x4 acc[3] = {};
  for (int c0 = 0; c0 < C_; c0 += 32) {
    float4 a0 = *(const float4*)(xp + c0);
    float4 a1 = *(const float4*)(xp + c0 + 4);
    Frag8 af;
    af.s[0] = bfbits(a0.x); af.s[1] = bfbits(a0.y);
    af.s[2] = bfbits(a0.z); af.s[3] = bfbits(a0.w);
    af.s[4] = bfbits(a1.x); af.s[5] = bfbits(a1.y);
    af.s[6] = bfbits(a1.z); af.s[7] = bfbits(a1.w);
#pragma unroll
    for (int f = 0; f < 3; ++f) {
      bf16x8 bfrag = ldb8(wp[f] + c0);
      acc[f] = __builtin_amdgcn_mfma_f32_16x16x32_bf16(af.b, bfrag, acc[f], 0, 0, 0);
    }
  }

  const int bb = (int)(blockIdx.x >> 8);          // 256 blocks per batch
  const int t0 = (int)(row0 - (size_t)bb * T_) + quad * 4;
#pragma unroll
  for (int f = 0; f < 3; ++f) {
    int gcol = wave * 48 + f * 16;
    int mat = gcol >> 6, hb = gcol & 63;
    int h = hb + q16;
    if (mat == 2) {                               // V: store transposed
      ushort4 v;
      v.x = bfbits(acc[f][0]); v.y = bfbits(acc[f][1]);
      v.z = bfbits(acc[f][2]); v.w = bfbits(acc[f][3]);
      *(ushort4*)(Vt + ((size_t)bb * H_ + h) * T_ + t0) = v;
    } else {
      float scale = (mat == 0) ? 0.125f : 1.0f;   // Q pre-scaled by 1/sqrt(64)
#pragma unroll
      for (int r = 0; r < 4; ++r) {
        size_t row = row0 + quad * 4 + r;         // C/D layout: row = quad*4+reg
        qkv[(size_t)mat * 1048576 + row * H_ + h] = bfbits(acc[f][r] * scale);
      }
    }
  }
}

// ---------------- k2: flash causal attention, in-block split-K --------------
// One block per 16-row q-tile; 4 waves take strided 64-row k-tiles with
// private (m,l,O); flash-merge through LDS at the end.
// S^T = K Q^T via mfma(A=K, B=Q): C layout holds S^T[kk=quad*4+reg][q=lane&15].
__global__ __launch_bounds__(256) void attn(const unsigned short* __restrict__ Q,
                                            const unsigned short* __restrict__ K,
                                            const unsigned short* __restrict__ Vt,
                                            float* __restrict__ out) {
  __shared__ float ml_s[2][4][16];
  __shared__ float o_s[4][16][68];                // +4 pad: 2-way max on banks
  const int lane = threadIdx.x & 63;
  const int wave = threadIdx.x >> 6;
  const int b = blockIdx.x;                       // batch
  const int tile = 255 - blockIdx.y;              // longest blocks dispatch first
  const int q16 = lane & 15, quad = lane >> 4;

  const unsigned short* Qb = Q + (size_t)b * T_ * H_;
  const unsigned short* Kb = K + (size_t)b * T_ * H_;
  const unsigned short* Vtb = Vt + (size_t)b * H_ * T_;

  const int q0 = tile * 16;
  bf16x8 qf0 = ldb8(Qb + (size_t)(q0 + q16) * H_ + quad * 8);
  bf16x8 qf1 = ldb8(Qb + (size_t)(q0 + q16) * H_ + 32 + quad * 8);

  f32x4 o0 = {0.f, 0.f, 0.f, 0.f}, o1 = o0, o2 = o0, o3 = o0;
  float m = -3.0e38f, l = 0.0f;
  const int ktiles = (tile >> 2) + 1;

  for (int kt = wave; kt < ktiles; kt += 4) {
    const int kkb = kt * 64;
    f32x4 st[4];
#pragma unroll
    for (int kb = 0; kb < 4; ++kb) {
      const unsigned short* kp = Kb + (size_t)(kkb + kb * 16 + q16) * H_ + quad * 8;
      bf16x8 ka0 = ldb8(kp);
      bf16x8 ka1 = ldb8(kp + 32);
      f32x4 s = {0.f, 0.f, 0.f, 0.f};
      s = __builtin_amdgcn_mfma_f32_16x16x32_bf16(ka0, qf0, s, 0, 0, 0);
      s = __builtin_amdgcn_mfma_f32_16x16x32_bf16(ka1, qf1, s, 0, 0, 0);
      st[kb] = s;
    }
    if (kt == ktiles - 1) {                       // diagonal tile: causal mask
      const int q_abs = q0 + q16;
#pragma unroll
      for (int kb = 0; kb < 4; ++kb)
#pragma unroll
        for (int r = 0; r < 4; ++r) {
          int kk_abs = kkb + kb * 16 + quad * 4 + r;
          if (kk_abs > q_abs) st[kb][r] = -3.0e38f;
        }
    }
    // row stats: per-lane q = q16; kk spread over regs (in-lane) + quads (xor)
    float mloc = fmaxf(fmaxf(st[0][0], st[0][1]), fmaxf(st[0][2], st[0][3]));
#pragma unroll
    for (int kb = 1; kb < 4; ++kb)
      mloc = fmaxf(mloc, fmaxf(fmaxf(st[kb][0], st[kb][1]), fmaxf(st[kb][2], st[kb][3])));
    mloc = fmaxf(mloc, __shfl_xor(mloc, 16));
    mloc = fmaxf(mloc, __shfl_xor(mloc, 32));
    float mnew = fmaxf(m, mloc);
    float alpha = __expf(m - mnew);
    float lsum = 0.f;
    unsigned pk[4][2];
#pragma unroll
    for (int kb = 0; kb < 4; ++kb) {
      float p0 = __expf(st[kb][0] - mnew);
      float p1 = __expf(st[kb][1] - mnew);
      float p2 = __expf(st[kb][2] - mnew);
      float p3 = __expf(st[kb][3] - mnew);
      lsum += (p0 + p1) + (p2 + p3);
      pk[kb][0] = (unsigned)bfbits(p0) | ((unsigned)bfbits(p1) << 16);
      pk[kb][1] = (unsigned)bfbits(p2) | ((unsigned)bfbits(p3) << 16);
    }
    lsum += __shfl_xor(lsum, 16);
    lsum += __shfl_xor(lsum, 32);
    l = l * alpha + lsum;
    m = mnew;
    // rescale O: row of o-frag = quad*4+reg; alpha lives at lane==row (quad 0)
    float ar0 = __shfl(alpha, quad * 4 + 0);
    float ar1 = __shfl(alpha, quad * 4 + 1);
    float ar2 = __shfl(alpha, quad * 4 + 2);
    float ar3 = __shfl(alpha, quad * 4 + 3);
    o0[0] *= ar0; o0[1] *= ar1; o0[2] *= ar2; o0[3] *= ar3;
    o1[0] *= ar0; o1[1] *= ar1; o1[2] *= ar2; o1[3] *= ar3;
    o2[0] *= ar0; o2[1] *= ar1; o2[2] *= ar2; o2[3] *= ar3;
    o3[0] *= ar0; o3[1] *= ar1; o3[2] *= ar2; o3[3] *= ar3;

    // P^T (C layout) -> PV A-operand layout (K=32): half-quad exchange
    const int kbsel = quad >> 1;
    const int src0 = q16 + 32 * (quad & 1);
#pragma unroll
    for (int kb2 = 0; kb2 < 2; ++kb2) {
      int xA = __shfl((int)pk[2 * kb2][0], src0);
      int xB = __shfl((int)pk[2 * kb2 + 1][0], src0);
      int yA = __shfl((int)pk[2 * kb2][1], src0);
      int yB = __shfl((int)pk[2 * kb2 + 1][1], src0);
      int zA = __shfl((int)pk[2 * kb2][0], src0 + 16);
      int zB = __shfl((int)pk[2 * kb2 + 1][0], src0 + 16);
      int wA = __shfl((int)pk[2 * kb2][1], src0 + 16);
      int wB = __shfl((int)pk[2 * kb2 + 1][1], src0 + 16);
      Frag8 pf;
      pf.u.x = (unsigned)(kbsel ? xB : xA);
      pf.u.y = (unsigned)(kbsel ? yB : yA);
      pf.u.z = (unsigned)(kbsel ? zB : zA);
      pf.u.w = (unsigned)(kbsel ? wB : wA);
      const unsigned short* vp = Vtb + (size_t)q16 * T_ + kkb + kb2 * 32 + quad * 8;
      o0 = __builtin_amdgcn_mfma_f32_16x16x32_bf16(pf.b, ldb8(vp), o0, 0, 0, 0);
      o1 = __builtin_amdgcn_mfma_f32_16x16x32_bf16(pf.b, ldb8(vp + (size_t)16 * T_), o1, 0, 0, 0);
      o2 = __builtin_amdgcn_mfma_f32_16x16x32_bf16(pf.b, ldb8(vp + (size_t)32 * T_), o2, 0, 0, 0);
      o3 = __builtin_amdgcn_mfma_f32_16x16x32_bf16(pf.b, ldb8(vp + (size_t)48 * T_), o3, 0, 0, 0);
    }
  }

  // ---- flash merge across the 4 waves ----
  if (quad == 0) { ml_s[0][wave][q16] = m; ml_s[1][wave][q16] = l; }
  __syncthreads();
  float M = fmaxf(fmaxf(ml_s[0][0][q16], ml_s[0][1][q16]),
                  fmaxf(ml_s[0][2][q16], ml_s[0][3][q16]));
  float beta = __expf(m - M);                     // 0 for waves with no work
  float b0 = __shfl(beta, quad * 4 + 0);
  float b1 = __shfl(beta, quad * 4 + 1);
  float b2 = __shfl(beta, quad * 4 + 2);
  float b3 = __shfl(beta, quad * 4 + 3);
  o0[0] *= b0; o0[1] *= b1; o0[2] *= b2; o0[3] *= b3;
  o1[0] *= b0; o1[1] *= b1; o1[2] *= b2; o1[3] *= b3;
  o2[0] *= b0; o2[1] *= b1; o2[2] *= b2; o2[3] *= b3;
  o3[0] *= b0; o3[1] *= b1; o3[2] *= b2; o3[3] *= b3;
#pragma unroll
  for (int r = 0; r < 4; ++r) {
    o_s[wave][quad * 4 + r][q16 + 0]  = o0[r];
    o_s[wave][quad * 4 + r][q16 + 16] = o1[r];
    o_s[wave][quad * 4 + r][q16 + 32] = o2[r];
    o_s[wave][quad * 4 + r][q16 + 48] = o3[r];
  }
  __syncthreads();

  const int idx = threadIdx.x;
  const int row = idx >> 4;
  const int col0 = (idx & 15) * 4;
  float m0 = ml_s[0][0][row], m1 = ml_s[0][1][row];
  float m2 = ml_s[0][2][row], m3 = ml_s[0][3][row];
  float Mr = fmaxf(fmaxf(m0, m1), fmaxf(m2, m3));
  float lt = ml_s[1][0][row] * __expf(m0 - Mr) + ml_s[1][1][row] * __expf(m1 - Mr)
           + ml_s[1][2][row] * __expf(m2 - Mr) + ml_s[1][3][row] * __expf(m3 - Mr);
  float4 a0 = *(const float4*)&o_s[0][row][col0];
  float4 a1 = *(const float4*)&o_s[1][row][col0];
  float4 a2 = *(const float4*)&o_s[2][row][col0];
  float4 a3 = *(const float4*)&o_s[3][row][col0];
  float inv = 1.0f / lt;
  float4 r;
  r.x = (a0.x + a1.x + a2.x + a3.x) * inv;
  r.y = (a0.y + a1.y + a2.y + a3.y) * inv;
  r.z = (a0.z + a1.z + a2.z + a3.z) * inv;
  r.w = (a0.w + a1.w + a2.w + a3.w) * inv;
  *(float4*)(out + ((size_t)b * T_ + q0 + row) * H_ + col0) = r;
}

extern "C" void kernel_launch(void* const* d_in, const int* in_sizes, int n_in,
                              void* d_out, int out_size, void* d_ws, size_t ws_size,
                              hipStream_t stream) {
  const float* x  = (const float*)d_in[0];
  const float* Wq = (const float*)d_in[1];
  const float* Wk = (const float*)d_in[2];
  const float* Wv = (const float*)d_in[3];
  float* out = (float*)d_out;
  unsigned short* ws = (unsigned short*)d_ws;

  // ws layout (ushort units):
  //   [0, 196608)        Wb  (Q|K|V bf16 weights)
  //   [196608, +2*1048576)  Q,K bf16 [B*T][64]  (Q pre-scaled)
  //   next 1048576       Vt bf16 [B][64][T]
  unsigned short* Wb  = ws;
  unsigned short* qkv = ws + 196608;
  unsigned short* Vt  = qkv + (size_t)2 * 1048576;

  wconv<<<192, 256, 0, stream>>>(Wq, Wk, Wv, Wb);
  qkv_proj<<<1024, 256, 0, stream>>>(x, Wb, qkv, Vt);
  attn<<<dim3(4, 256), 256, 0, stream>>>(qkv, qkv + 1048576, Vt, out);
}